// Round 3
// baseline (119.441 us; speedup 1.0000x reference)
//
#include <hip/hip_runtime.h>

// DLRM InteractionArch: B=32768, F=26, D=128.
// Per row: X = [dense; sparse] (27x128 f32), G = X X^T, out = [dense(128) | triu(G,k=1)(351)].
// One wave per batch row, single 32x32 MFMA tile (27<=32), LDS-free:
// each lane loads its fragment directly from global (A-frag == B-frag for a
// Gram matrix, so the internal k-permutation cancels).
// Truncation split x = h + l (h = top 16 bits, l = RNE(x-h)): G = hh^T + hl^T + lh^T.
// __launch_bounds__(256,8): target <=64 VGPR -> 8 waves/EU (occupancy quantum
// steps at 64/128/256 VGPR, so 65..128 all give only 4 waves/EU).

typedef __bf16 bf16x8 __attribute__((ext_vector_type(8)));
typedef float  f32x4  __attribute__((ext_vector_type(4)));
typedef float  f32x16 __attribute__((ext_vector_type(16)));

#define WAVES 4   // batch rows per block (one wave each)

// offset of pair (i,j), i<j, in row-major triu(27, k=1)
__device__ __forceinline__ int tri(int i, int j) {
    return i * 26 - (i * (i - 1)) / 2 + (j - i - 1);
}

// truncation split: h = x's top 16 bits (bf16 toward zero), l = RNE(x - h).
// x - h is exact (low mantissa bits), so x ~= h + l with |err| ~ 2^-16 |x|.
__device__ __forceinline__ void split(float x, __bf16& h, __bf16& l) {
    union { float f; unsigned int u; } v; v.f = x;
    unsigned int hu = v.u & 0xFFFF0000u;
    union { unsigned int u; float f; } hv; hv.u = hu;
    union { unsigned int u; unsigned short s[2]; __bf16 b[2]; } hb; hb.u = hu;
    h = hb.b[1];
    l = (__bf16)(x - hv.f);
}

__global__ __launch_bounds__(64 * WAVES, 8)
void dlrm_interact(const float* __restrict__ dense,
                   const float* __restrict__ sparse,
                   float* __restrict__ out)
{
    const int lane = threadIdx.x & 63;
    const int wid  = threadIdx.x >> 6;
    const int b    = blockIdx.x * WAVES + wid;

    const float* dRow = dense  + (size_t)b * 128;
    const float* sRow = sparse + (size_t)b * 3328;   // 26*128
    float*       oRow = out    + (size_t)b * 479;

    // ---- dense passthrough (exact fp32; out rows are only 4B-aligned) ----
    if (lane < 32) {
        const f32x4 v = *(const f32x4*)(dRow + 4 * lane);
        oRow[4 * lane + 0] = v[0];
        oRow[4 * lane + 1] = v[1];
        oRow[4 * lane + 2] = v[2];
        oRow[4 * lane + 3] = v[3];
    }

    // ---- per-lane fragment addressing (32x32x16 bf16) ----
    // A/B frag: lane holds row (lane&31), 8 consecutive k at (lane>>5)*8 + 16s.
    // Rows >=27 clamp to 26: garbage lands only in unstored output slots, and
    // duplicate addresses coalesce within the wave (no extra HBM traffic).
    const int r  = lane & 31;
    const int rc = r < 27 ? r : 26;
    const int cb = (lane >> 5) * 8;

    const float* xr = (rc == 0) ? dRow : (sRow + (rc - 1) * 128);

    f32x16 acc = {};

#pragma unroll
    for (int s = 0; s < 8; ++s) {
        const int c = cb + 16 * s;
        const f32x4 ua = *(const f32x4*)(xr + c);
        const f32x4 ub = *(const f32x4*)(xr + c + 4);

        bf16x8 Fh, Fl;
#pragma unroll
        for (int e = 0; e < 4; ++e) {
            __bf16 h, l;
            split(ua[e], h, l);  Fh[e]     = h;  Fl[e]     = l;
            split(ub[e], h, l);  Fh[e + 4] = h;  Fl[e + 4] = l;
        }

        acc = __builtin_amdgcn_mfma_f32_32x32x16_bf16(Fh, Fh, acc, 0, 0, 0);
        acc = __builtin_amdgcn_mfma_f32_32x32x16_bf16(Fh, Fl, acc, 0, 0, 0);
        acc = __builtin_amdgcn_mfma_f32_32x32x16_bf16(Fl, Fh, acc, 0, 0, 0);
    }

    // ---- write triu: C/D layout col=lane&31, row=(reg&3)+8*(reg>>2)+4*(lane>>5)
    //      [m74/m101-verified] ----
    const int j  = lane & 31;
    const int h4 = (lane >> 5) * 4;
    if (j < 27) {
#pragma unroll
        for (int reg = 0; reg < 16; ++reg) {
            const int i = (reg & 3) + 8 * (reg >> 2) + h4;
            if (i < j)
                oRow[128 + tri(i, j)] = acc[reg];
        }
    }
}

extern "C" void kernel_launch(void* const* d_in, const int* in_sizes, int n_in,
                              void* d_out, int out_size, void* d_ws, size_t ws_size,
                              hipStream_t stream) {
    const float* dense  = (const float*)d_in[0];
    const float* sparse = (const float*)d_in[1];
    float*       out    = (float*)d_out;

    const int B = in_sizes[0] / 128;          // 32768
    dim3 grid(B / WAVES), block(64 * WAVES);
    hipLaunchKernelGGL(dlrm_interact, grid, block, 0, stream, dense, sparse, out);
}

// Round 4
// 98.567 us; speedup vs baseline: 1.2118x; 1.2118x over previous
//
#include <hip/hip_runtime.h>

// DLRM InteractionArch: B=32768, F=26, D=128.
// Per row: X = [dense; sparse] (27x128 f32), G = X X^T, out = [dense(128) | triu(G,k=1)(351)].
// One wave per batch row; LDS-free: each lane loads its MFMA fragment directly
// from global (A-frag == B-frag for a Gram matrix, so k-permutation cancels).
// Round 4: round-2 16x16 structure (106us) + explicit load-prefetch phase:
// all 16 dwordx4 loads issued back-to-back before any convert/MFMA, to keep
// ~16 loads in flight per wave (HBM latency hiding at 4 waves/EU).
// Truncation split x = h + l: G = hh^T + hl^T + lh^T (lo*lo dropped).

typedef __bf16 bf16x8 __attribute__((ext_vector_type(8)));
typedef float  f32x4  __attribute__((ext_vector_type(4)));

#define WAVES 4   // batch rows per block (one wave each)

// offset of pair (i,j), i<j, in row-major triu(27, k=1)
__device__ __forceinline__ int tri(int i, int j) {
    return i * 26 - (i * (i - 1)) / 2 + (j - i - 1);
}

// truncation split: h = x's top 16 bits (bf16 toward zero), l = RNE(x - h).
// x - h is exact, so x ~= h + l with |err| ~ 2^-16 |x|.
__device__ __forceinline__ void split(float x, __bf16& h, __bf16& l) {
    union { float f; unsigned int u; } v; v.f = x;
    unsigned int hu = v.u & 0xFFFF0000u;
    union { unsigned int u; float f; } hv; hv.u = hu;
    union { unsigned int u; __bf16 b[2]; } hb; hb.u = hu;
    h = hb.b[1];
    l = (__bf16)(x - hv.f);
}

__device__ __forceinline__ void cvt8(const f32x4 a, const f32x4 b,
                                     bf16x8& H, bf16x8& L) {
#pragma unroll
    for (int e = 0; e < 4; ++e) {
        __bf16 h, l;
        split(a[e], h, l);   H[e]     = h; L[e]     = l;
        split(b[e], h, l);   H[e + 4] = h; L[e + 4] = l;
    }
}

__global__ __launch_bounds__(64 * WAVES, 4)
void dlrm_interact(const float* __restrict__ dense,
                   const float* __restrict__ sparse,
                   float* __restrict__ out)
{
    const int lane = threadIdx.x & 63;
    const int wid  = threadIdx.x >> 6;
    const int b    = blockIdx.x * WAVES + wid;

    const float* dRow = dense  + (size_t)b * 128;
    const float* sRow = sparse + (size_t)b * 3328;   // 26*128
    float*       oRow = out    + (size_t)b * 479;

    // ---- per-lane fragment addressing ----
    // A/B frag of mfma_f32_16x16x32_bf16: lane holds row (lane&15) [tile0] /
    // 16+(lane&15) clamped [tile1], cols (lane>>4)*8 + 32*s .. +7.
    const int r0 = lane & 15;
    const int cc = lane >> 4;
    const int r1 = 16 + (r0 < 11 ? r0 : 10);  // clamp; garbage lands in unstored outputs

    const float* x0 = (r0 == 0) ? dRow : (sRow + (r0 - 1) * 128);
    const float* x1 = sRow + (r1 - 1) * 128;

    // ---- prefetch phase: issue all 16 fragment loads back-to-back ----
    f32x4 L0a[4], L0b[4], L1a[4], L1b[4];
#pragma unroll
    for (int s = 0; s < 4; ++s) {
        const int c = cc * 8 + 32 * s;
        L0a[s] = *(const f32x4*)(x0 + c);
        L0b[s] = *(const f32x4*)(x0 + c + 4);
        L1a[s] = *(const f32x4*)(x1 + c);
        L1b[s] = *(const f32x4*)(x1 + c + 4);
    }

    // ---- dense passthrough (exact fp32; out rows are only 4B-aligned) ----
    if (lane < 32) {
        const f32x4 v = *(const f32x4*)(dRow + 4 * lane);
        oRow[4 * lane + 0] = v[0];
        oRow[4 * lane + 1] = v[1];
        oRow[4 * lane + 2] = v[2];
        oRow[4 * lane + 3] = v[3];
    }

    // ---- convert + MFMA pipeline (consumes loads in issue order) ----
    f32x4 a00 = {0.f, 0.f, 0.f, 0.f};
    f32x4 a01 = {0.f, 0.f, 0.f, 0.f};
    f32x4 a11 = {0.f, 0.f, 0.f, 0.f};

#pragma unroll
    for (int s = 0; s < 4; ++s) {
        bf16x8 F0h, F0l, F1h, F1l;
        cvt8(L0a[s], L0b[s], F0h, F0l);
        cvt8(L1a[s], L1b[s], F1h, F1l);

        a00 = __builtin_amdgcn_mfma_f32_16x16x32_bf16(F0h, F0h, a00, 0, 0, 0);
        a00 = __builtin_amdgcn_mfma_f32_16x16x32_bf16(F0h, F0l, a00, 0, 0, 0);
        a00 = __builtin_amdgcn_mfma_f32_16x16x32_bf16(F0l, F0h, a00, 0, 0, 0);

        a01 = __builtin_amdgcn_mfma_f32_16x16x32_bf16(F0h, F1h, a01, 0, 0, 0);
        a01 = __builtin_amdgcn_mfma_f32_16x16x32_bf16(F0h, F1l, a01, 0, 0, 0);
        a01 = __builtin_amdgcn_mfma_f32_16x16x32_bf16(F0l, F1h, a01, 0, 0, 0);

        a11 = __builtin_amdgcn_mfma_f32_16x16x32_bf16(F1h, F1h, a11, 0, 0, 0);
        a11 = __builtin_amdgcn_mfma_f32_16x16x32_bf16(F1h, F1l, a11, 0, 0, 0);
        a11 = __builtin_amdgcn_mfma_f32_16x16x32_bf16(F1l, F1h, a11, 0, 0, 0);
    }

    // ---- write triu: C/D layout col=lane&15, row=(lane>>4)*4+reg [m89-verified] ----
    const int rb = cc * 4;
#pragma unroll
    for (int r = 0; r < 4; ++r) {
        const int i = rb + r;
        if (i < r0)                          // G00: (i, r0), i < r0 < 16
            oRow[128 + tri(i, r0)] = a00[r];
        if (r0 < 11)                         // G01: (i, 16+r0), i < 16 <= j
            oRow[128 + tri(i, 16 + r0)] = a01[r];
        if (r0 < 11 && i < r0)               // G11: (16+i, 16+r0)
            oRow[128 + tri(16 + i, 16 + r0)] = a11[r];
    }
}

extern "C" void kernel_launch(void* const* d_in, const int* in_sizes, int n_in,
                              void* d_out, int out_size, void* d_ws, size_t ws_size,
                              hipStream_t stream) {
    const float* dense  = (const float*)d_in[0];
    const float* sparse = (const float*)d_in[1];
    float*       out    = (float*)d_out;

    const int B = in_sizes[0] / 128;          // 32768
    dim3 grid(B / WAVES), block(64 * WAVES);
    hipLaunchKernelGGL(dlrm_interact, grid, block, 0, stream, dense, sparse, out);
}